// Round 1
// 468.539 us; speedup vs baseline: 1.0008x; 1.0008x over previous
//
#include <hip/hip_runtime.h>
#include <hip/hip_bf16.h>
#include <math.h>

#define D_MODEL 4096
#define D_FF    11008
#define F4      (D_FF / 4)       // 2752 float4 columns in Wgatet rows
#define D4      (D_MODEL / 4)    // 1024 float4 columns in Wup/Wdownt rows

#define G_CHUNK   64                     // rows per gate chunk
#define G_NCHUNK  (D_MODEL / G_CHUNK)    // 64 partials -> one per lane in k2
#define DN_ROWS   64                     // d_ff rows per down chunk
#define DN_NCHUNK (D_FF / DN_ROWS)       // 172 down partials

// ---------------------------------------------------------------------------
// Kernel 1: gate partials.  gpart[c][j] = sum_{i in chunk c} x[i]*Wgatet[i][j]
// Rank-1-update decomposition; each thread owns one float4 of columns, each
// block one 64-row chunk. unroll 4 -> 16 independent 16B loads in flight per
// thread per burst. Coalesced loads+stores, NO atomics, NO zero-init.
// ---------------------------------------------------------------------------
__global__ __launch_bounds__(256) void gate_part_k(const float* __restrict__ x,
                                                   const float* __restrict__ Wg,
                                                   float* __restrict__ gpart) {
    const int j4 = blockIdx.x * 256 + threadIdx.x;   // float4 column index
    const int i0 = blockIdx.y * G_CHUNK;
    const float4* __restrict__ W4 = (const float4*)Wg;

    if (j4 < F4) {
        float4 acc = make_float4(0.f, 0.f, 0.f, 0.f);
#pragma unroll 4
        for (int i = i0; i < i0 + G_CHUNK; i += 4) {
            const float4 xv = *(const float4*)(x + i);    // wave-uniform, L1-hit
            float4 w;
            w = W4[(size_t)(i + 0) * F4 + j4];
            acc.x += xv.x * w.x; acc.y += xv.x * w.y; acc.z += xv.x * w.z; acc.w += xv.x * w.w;
            w = W4[(size_t)(i + 1) * F4 + j4];
            acc.x += xv.y * w.x; acc.y += xv.y * w.y; acc.z += xv.y * w.z; acc.w += xv.y * w.w;
            w = W4[(size_t)(i + 2) * F4 + j4];
            acc.x += xv.z * w.x; acc.y += xv.z * w.y; acc.z += xv.z * w.z; acc.w += xv.z * w.w;
            w = W4[(size_t)(i + 3) * F4 + j4];
            acc.x += xv.w * w.x; acc.y += xv.w * w.y; acc.z += xv.w * w.z; acc.w += xv.w * w.w;
        }
        *(float4*)(gpart + (size_t)blockIdx.y * D_FF + 4 * (size_t)j4) = acc;
    }
}

// ---------------------------------------------------------------------------
// Kernel 2: reduce 64 gate partials (exactly one per lane) -> raw;
// x1 = silu(raw); if |x1| > thr: z[j] = dot(x, Wup[j,:]) * x1, else 0.
// One 64-lane wave per d_ff row; whole wave early-outs on unflagged rows
// (skips the 16 KB Wup row read). 16 independent 16B loads in flight.
// ---------------------------------------------------------------------------
__global__ __launch_bounds__(256) void up_gemv_k(const float* __restrict__ x,
                                                 const float* __restrict__ Wup,
                                                 const float* __restrict__ gpart,
                                                 const float* __restrict__ thr_p,
                                                 float* __restrict__ z) {
    const int wave = threadIdx.x >> 6;
    const int lane = threadIdx.x & 63;
    const int j = blockIdx.x * 4 + wave;   // D_FF = 2752 blocks * 4 waves

    // one partial per lane (G_NCHUNK == 64), butterfly to broadcast raw[j]
    float r = gpart[(size_t)lane * D_FF + j];
#pragma unroll
    for (int off = 32; off > 0; off >>= 1)
        r += __shfl_xor(r, off);

    const float x1  = r / (1.0f + __expf(-r));   // silu
    const float thr = *thr_p;

    if (!(fabsf(x1) > thr)) {
        if (lane == 0) z[j] = 0.0f;
        return;
    }

    const float4* __restrict__ A = (const float4*)(Wup + (size_t)j * D_MODEL);
    const float4* __restrict__ X = (const float4*)x;
    float acc = 0.0f;
#pragma unroll
    for (int k = 0; k < 16; ++k) {
        const float4 a  = A[k * 64 + lane];
        const float4 xv = X[k * 64 + lane];
        acc += a.x * xv.x + a.y * xv.y + a.z * xv.z + a.w * xv.w;
    }
#pragma unroll
    for (int off = 32; off > 0; off >>= 1)
        acc += __shfl_down(acc, off);

    if (lane == 0) z[j] = acc * x1;
}

// ---------------------------------------------------------------------------
// Kernel 3: down partials, column-tiled rank-1 update (same shape as k1).
// Block (bx,by): float4 columns [bx*256, bx*256+256), rows [by*64, by*64+64).
// BRANCHLESS: z[j]==0 rows contribute exact zeros; multiply beats the
// wave-uniform branch because unroll 8 keeps 8 independent loads in flight
// (fixes the latency-bound 2-loads-in-flight serial loop of the old k3).
// 688 blocks (~11 waves/CU). NO atomics.
// ---------------------------------------------------------------------------
__global__ __launch_bounds__(256) void down_part_k(const float* __restrict__ z,
                                                   const float* __restrict__ Wd,
                                                   float* __restrict__ dpart) {
    const int c4 = blockIdx.x * 256 + threadIdx.x;   // 0..1023 float4 column
    const int j0 = blockIdx.y * DN_ROWS;
    const float4* __restrict__ W4 = (const float4*)Wd;

    float4 acc = make_float4(0.f, 0.f, 0.f, 0.f);
#pragma unroll 8
    for (int r = 0; r < DN_ROWS; ++r) {
        const int j = j0 + r;
        const float  zj = z[j];                       // wave-uniform (s_load)
        const float4 w  = W4[(size_t)j * D4 + c4];
        acc.x += zj * w.x; acc.y += zj * w.y; acc.z += zj * w.z; acc.w += zj * w.w;
    }
    ((float4*)dpart)[(size_t)blockIdx.y * D4 + c4] = acc;
}

// ---------------------------------------------------------------------------
// Kernel 4: out[i] = sum_{b=0..171} dpart[b][i].  2.75 MB, cache-resident.
// 32 blocks; block g owns 32 float4 columns; 8 slices stride over the 172
// partials, LDS tree finish. Writes every output exactly once.
// ---------------------------------------------------------------------------
__global__ __launch_bounds__(256) void down_reduce_k(const float* __restrict__ dpart,
                                                     float* __restrict__ out) {
    const int t     = threadIdx.x;
    const int col   = (t & 31);          // 0..31 within this block's column tile
    const int slice = (t >> 5);          // 0..7
    const int c4    = blockIdx.x * 32 + col;   // global float4 column

    const float4* __restrict__ dp = (const float4*)dpart;
    float4 acc = make_float4(0.f, 0.f, 0.f, 0.f);
    for (int b = slice; b < DN_NCHUNK; b += 8) {
        const float4 v = dp[(size_t)b * D4 + c4];
        acc.x += v.x; acc.y += v.y; acc.z += v.z; acc.w += v.w;
    }

    __shared__ float4 red[256];
    red[t] = acc;
    __syncthreads();
    if (t < 32) {
        float4 r = red[t];
#pragma unroll
        for (int s = 1; s < 8; ++s) {
            const float4 v = red[t + 32 * s];
            r.x += v.x; r.y += v.y; r.z += v.z; r.w += v.w;
        }
        ((float4*)out)[c4] = r;
    }
}

// ---------------------------------------------------------------------------
extern "C" void kernel_launch(void* const* d_in, const int* in_sizes, int n_in,
                              void* d_out, int out_size, void* d_ws, size_t ws_size,
                              hipStream_t stream) {
    const float* x    = (const float*)d_in[0];   // [1,1,4096]
    const float* Wup  = (const float*)d_in[1];   // [11008, 4096]
    const float* Wg   = (const float*)d_in[2];   // [4096, 11008]
    const float* Wd   = (const float*)d_in[3];   // [11008, 4096]
    const float* thr  = (const float*)d_in[4];   // scalar
    float* out = (float*)d_out;                  // [1,1,4096]

    float* gpart = (float*)d_ws;                         // 64 * 11008 floats (2.75 MB)
    float* z     = gpart + (size_t)G_NCHUNK * D_FF;      // 11008 floats
    float* dpart = z + D_FF;                             // 172 * 4096 floats (2.75 MB)

    // 1) gate partials: 11 column-tiles x 64 row-chunks
    gate_part_k<<<dim3(11, G_NCHUNK), 256, 0, stream>>>(x, Wg, gpart);

    // 2) z = flag ? (x @ Wup^T) * silu(raw) : 0
    up_gemv_k<<<D_FF / 4, 256, 0, stream>>>(x, Wup, gpart, thr, z);

    // 3) down partials: 4 column-tiles x 172 row-chunks, branchless
    down_part_k<<<dim3(4, DN_NCHUNK), 256, 0, stream>>>(z, Wd, dpart);

    // 4) out = column-sum of partials
    down_reduce_k<<<D4 / 32, 256, 0, stream>>>(dpart, out);
}